// Round 2
// baseline (5816.413 us; speedup 1.0000x reference)
//
#include <hip/hip_runtime.h>
#include <hip/hip_bf16.h>

typedef unsigned short u16;
typedef unsigned int u32;
typedef unsigned long long u64;
using bf16x8 = __attribute__((ext_vector_type(8))) short;
using f32x4  = __attribute__((ext_vector_type(4))) float;

__device__ inline u16 f2bf(float f) {
  union { float f; unsigned u; } v; v.f = f;
  unsigned u = v.u;
  unsigned r = (u + 0x7FFFu + ((u >> 16) & 1u)) >> 16;
  return (u16)r;
}
__device__ inline float bf2f(u16 b) {
  union { unsigned u; float f; } v; v.u = ((unsigned)b) << 16;
  return v.f;
}
__device__ inline float sigf(float x) { return 1.0f / (1.0f + __expf(-x)); }
__device__ inline float tanhfast(float x) { return 1.0f - 2.0f / (__expf(2.0f * x) + 1.0f); }

// ---------------- prep kernels ----------------

__global__ void cvt_bf16(const float* __restrict__ in, u16* __restrict__ out, int n) {
  for (int i = blockIdx.x * 256 + threadIdx.x; i < n; i += gridDim.x * 256)
    out[i] = f2bf(in[i]);
}

// G[j][c] = sum_i fc2w[i*256+j] * Avec[i][c]
__global__ __launch_bounds__(256) void gmat_kernel(const float* __restrict__ fc2w,
                                                   const float* __restrict__ dw,
                                                   float* __restrict__ G) {
  int j = threadIdx.x;
  float g0 = 0.f, g1 = 0.f, g2 = 0.f;
  for (int i = 0; i < 256; ++i) {
    float a0 = dw[i * 9 + 7] - dw[i * 9 + 5];  // M[2][1]
    float a1 = dw[i * 9 + 2] - dw[i * 9 + 6];  // M[0][2]
    float a2 = dw[i * 9 + 3] - dw[i * 9 + 1];  // M[1][0]
    float w = fc2w[i * 256 + j];
    g0 += w * a0; g1 += w * a1; g2 += w * a2;
  }
  G[j * 3 + 0] = g0; G[j * 3 + 1] = g1; G[j * 3 + 2] = g2;
}

// ---------------- fc1_1 (chunked over T) ----------------

__global__ __launch_bounds__(256) void fc1_kernel(const float* __restrict__ X,
                                                  const float* __restrict__ W1,
                                                  const float* __restrict__ b1,
                                                  u16* __restrict__ H1, int t0, int tcl2) {
  __shared__ float w1s[256 * 9];
  int tid = threadIdx.x;
  for (int idx = tid; idx < 2048; idx += 256)
    w1s[(idx >> 3) * 9 + (idx & 7)] = W1[idx];
  __syncthreads();
  float wreg[8];
#pragma unroll
  for (int i = 0; i < 8; ++i) wreg[i] = w1s[tid * 9 + i];
  float bb = b1[tid];
  int Tc = 1 << tcl2;
  int row0 = blockIdx.x * 64;
  for (int r = 0; r < 64; ++r) {
    int rl = row0 + r;
    int b = rl >> tcl2, tp = rl & (Tc - 1);
    const float4* xr = (const float4*)(X + ((size_t)b * 2048 + t0 + tp) * 8);
    float4 xa = xr[0], xb = xr[1];
    float acc = bb + xa.x * wreg[0] + xa.y * wreg[1] + xa.z * wreg[2] + xa.w * wreg[3]
                   + xb.x * wreg[4] + xb.y * wreg[5] + xb.z * wreg[6] + xb.w * wreg[7];
    H1[(size_t)rl * 256 + tid] = f2bf(fmaxf(acc, 0.f));
  }
}

// ---------------- bf16 MFMA GEMM, K=256 ----------------
// out[M x N] = act(A[M x 256] @ Bw[N x 256]^T + bias0 (+ bias1))
__global__ __launch_bounds__(256) void gemm_k256(const u16* __restrict__ A,
                                                 const u16* __restrict__ Bw,
                                                 const float* __restrict__ bias0,
                                                 const float* __restrict__ bias1,
                                                 u16* __restrict__ out, int N, int relu) {
  int tid = threadIdx.x;
  int lane = tid & 63, wv = tid >> 6;
  int lr = lane & 15, lk = lane >> 4;
  int nblk = N >> 6;
  int mb = blockIdx.x / nblk, nb = blockIdx.x - mb * nblk;
  int R0 = mb * 128 + (wv >> 1) * 64;
  int C0 = nb * 64 + (wv & 1) * 32;
  f32x4 acc[4][2];
#pragma unroll
  for (int mt = 0; mt < 4; ++mt)
#pragma unroll
    for (int nt = 0; nt < 2; ++nt) acc[mt][nt] = (f32x4){0.f, 0.f, 0.f, 0.f};
#pragma unroll
  for (int kk = 0; kk < 8; ++kk) {
    int ko = 32 * kk + 8 * lk;
    bf16x8 af[4], bfr[2];
#pragma unroll
    for (int mt = 0; mt < 4; ++mt)
      af[mt] = *(const bf16x8*)(A + (size_t)(R0 + 16 * mt + lr) * 256 + ko);
#pragma unroll
    for (int nt = 0; nt < 2; ++nt)
      bfr[nt] = *(const bf16x8*)(Bw + (size_t)(C0 + 16 * nt + lr) * 256 + ko);
#pragma unroll
    for (int mt = 0; mt < 4; ++mt)
#pragma unroll
      for (int nt = 0; nt < 2; ++nt)
        acc[mt][nt] = __builtin_amdgcn_mfma_f32_16x16x32_bf16(af[mt], bfr[nt], acc[mt][nt], 0, 0, 0);
  }
#pragma unroll
  for (int nt = 0; nt < 2; ++nt) {
    int col = C0 + 16 * nt + lr;
    float bs = bias0[col] + (bias1 ? bias1[col] : 0.f);
#pragma unroll
    for (int mt = 0; mt < 4; ++mt) {
#pragma unroll
      for (int r = 0; r < 4; ++r) {
        int row = R0 + 16 * mt + 4 * lk + r;
        float v = acc[mt][nt][r] + bs;
        if (relu) v = fmaxf(v, 0.f);
        out[(size_t)row * N + col] = f2bf(v);
      }
    }
  }
}

// ---------------- persistent LSTM (chunked) ----------------
// 16 blocks x 512 thr. grp = bid&7 (8 batches), half = bid>>3 (512 gate rows).
// W_hh half held in VGPRs as MFMA B-frags. h exchanged between the pair via
// tagged agent-scope atomic u32 words: (bf16 h << 16) | (t+1), parity dbuf.
__global__ __launch_bounds__(512, 2) void lstm_kernel(const u16* __restrict__ xg,
                                                      const float* __restrict__ Whh,
                                                      const float* __restrict__ G,
                                                      float* __restrict__ wpart,
                                                      u32* __restrict__ hx,
                                                      float* __restrict__ cstate,
                                                      float* __restrict__ hstate,
                                                      int t0, int Tc) {
  __shared__ u16 h_lds[16][264];
  __shared__ float gates_lds[8][520];

  int tid = threadIdx.x;
  int lane = tid & 63, wv = tid >> 6;
  int lr = lane & 15, lk = lane >> 4;
  int grp = blockIdx.x & 7, half = blockIdx.x >> 3;
  int B0 = grp * 8;

  // W_hh fragments: local cols [64*wv, 64*wv+64), global rows via half-split
  bf16x8 wf[4][8];
#pragma unroll
  for (int n = 0; n < 4; ++n) {
#pragma unroll
    for (int kk = 0; kk < 8; ++kk) {
      int chat = 64 * wv + 16 * n + lr;
      int g = (chat >> 7) * 256 + 128 * half + (chat & 127);
      int k = 32 * kk + 8 * lk;
      const float* p = Whh + (size_t)g * 256 + k;
      bf16x8 v;
#pragma unroll
      for (int e = 0; e < 8; ++e) v[e] = (short)f2bf(p[e]);
      wf[n][kk] = v;
    }
  }
  for (int i = tid; i < 16 * 264; i += 512) ((u16*)h_lds)[i] = 0;

  u32* hxg = hx + (size_t)grp * (2 * 8 * 256);
  int j0 = 128 * half + lane;  // q=0 hidden index; q=1 is j0+64

  float cst[2], hp[2];
  if (t0 == 0) {
    cst[0] = cst[1] = hp[0] = hp[1] = 0.f;
  } else {
    size_t si = (size_t)(B0 + wv) * 256;
    cst[0] = cstate[si + j0]; cst[1] = cstate[si + j0 + 64];
    hp[0] = hstate[si + j0];  hp[1] = hstate[si + j0 + 64];
  }
  __syncthreads();  // h_lds zero-fill complete
  if (t0 > 0) {     // restore h_{t0-1} (both halves) from tagged exchange buf
    u32 expect = (u32)t0 & 0xFFFFu;
    int par = (t0 - 1) & 1;
#pragma unroll
    for (int w = 0; w < 2; ++w) {
      int v = tid * 4 + w * 2;
      int b = v >> 8, j = v & 255;
      u64* slot = (u64*)(hxg + ((size_t)(par * 8 + b) * 256 + j));
      u64 dv;
      do {
        dv = __hip_atomic_load(slot, __ATOMIC_RELAXED, __HIP_MEMORY_SCOPE_AGENT);
      } while ((u32)(dv & 0xFFFFu) != expect || (u32)((dv >> 32) & 0xFFFFu) != expect);
      h_lds[b][j] = (u16)(dv >> 16);
      h_lds[b][j + 1] = (u16)(dv >> 48);
    }
  }

  float Gr[2][3];
#pragma unroll
  for (int q = 0; q < 2; ++q) {
    int jg = 128 * half + 64 * q + lane;
#pragma unroll
    for (int c0 = 0; c0 < 3; ++c0) Gr[q][c0] = G[jg * 3 + c0];
  }
  u16 xn[8];
  {
    size_t xrow = (size_t)(B0 + wv) * Tc * 1024;
#pragma unroll
    for (int gt = 0; gt < 4; ++gt)
#pragma unroll
      for (int q = 0; q < 2; ++q)
        xn[gt * 2 + q] = xg[xrow + gt * 256 + 128 * half + 64 * q + lane];
  }
  // other-half poll coords for the in-loop exchange
  int ov = tid * 2;
  int ob = ov >> 7;
  int oj = 128 * (1 - half) + (ov & 127);
  __syncthreads();

  for (int tp = 0; tp < Tc; ++tp) {
    int t = t0 + tp;
    u16 xc[8];
#pragma unroll
    for (int i = 0; i < 8; ++i) xc[i] = xn[i];
    if (tp + 1 < Tc) {
      size_t xrow = ((size_t)(B0 + wv) * Tc + (tp + 1)) * 1024;
#pragma unroll
      for (int gt = 0; gt < 4; ++gt)
#pragma unroll
        for (int q = 0; q < 2; ++q)
          xn[gt * 2 + q] = xg[xrow + gt * 256 + 128 * half + 64 * q + lane];
    }
    // gates[b][chat] = sum_k h[b][k] * W[g(chat)][k]
    f32x4 acc[4];
#pragma unroll
    for (int n = 0; n < 4; ++n) acc[n] = (f32x4){0.f, 0.f, 0.f, 0.f};
#pragma unroll
    for (int kk = 0; kk < 8; ++kk) {
      bf16x8 af = *(const bf16x8*)&h_lds[lr][32 * kk + 8 * lk];
#pragma unroll
      for (int n = 0; n < 4; ++n)
        acc[n] = __builtin_amdgcn_mfma_f32_16x16x32_bf16(af, wf[n][kk], acc[n], 0, 0, 0);
    }
    if (lk < 2) {
#pragma unroll
      for (int n = 0; n < 4; ++n) {
        int chat = 64 * wv + 16 * n + lr;
#pragma unroll
        for (int r = 0; r < 4; ++r) gates_lds[4 * lk + r][chat] = acc[n][r];
      }
    }
    __syncthreads();
    // update phase: batch = wv, hidden j = 128*half + 64*q + lane
    float wa0 = 0.f, wa1 = 0.f, wa2 = 0.f;
#pragma unroll
    for (int q = 0; q < 2; ++q) {
      int jl = 64 * q + lane;
      float ig = sigf(bf2f(xc[0 + q]) + gates_lds[wv][0 + jl]);
      float fg = sigf(bf2f(xc[2 + q]) + gates_lds[wv][128 + jl]);
      float gg = tanhfast(bf2f(xc[4 + q]) + gates_lds[wv][256 + jl]);
      float og = sigf(bf2f(xc[6 + q]) + gates_lds[wv][384 + jl]);
      cst[q] = fg * cst[q] + ig * gg;
      float hn = og * tanhfast(cst[q]);
      float d = hn - hp[q]; hp[q] = hn;
      u16 hb = f2bf(hn);
      int j = 128 * half + jl;
      h_lds[wv][j] = hb;
      if (t < 2047)
        __hip_atomic_store(&hxg[((size_t)(t & 1) * 8 + wv) * 256 + j],
                           ((u32)hb << 16) | ((u32)(t + 1) & 0xFFFFu),
                           __ATOMIC_RELAXED, __HIP_MEMORY_SCOPE_AGENT);
      wa0 += d * Gr[q][0]; wa1 += d * Gr[q][1]; wa2 += d * Gr[q][2];
    }
#pragma unroll
    for (int off = 1; off < 64; off <<= 1) {
      wa0 += __shfl_xor(wa0, off);
      wa1 += __shfl_xor(wa1, off);
      wa2 += __shfl_xor(wa2, off);
    }
    if (lane == 0 && t >= 1) {
      size_t ro = (size_t)half * 64 * 2047 + (size_t)(B0 + wv) * 2047 + (t - 1);
      wpart[ro * 3 + 0] = wa0; wpart[ro * 3 + 1] = wa1; wpart[ro * 3 + 2] = wa2;
    }
    // pull other block's h half (skip at global end and at chunk end)
    if (t < 2047 && tp + 1 < Tc) {
      u32 expect = (u32)(t + 1) & 0xFFFFu;
      u64* slot = (u64*)(hxg + ((size_t)((t & 1) * 8 + ob) * 256 + oj));
      u64 dv;
      do {
        dv = __hip_atomic_load(slot, __ATOMIC_RELAXED, __HIP_MEMORY_SCOPE_AGENT);
      } while ((u32)(dv & 0xFFFFu) != expect || (u32)((dv >> 32) & 0xFFFFu) != expect);
      h_lds[ob][oj] = (u16)(dv >> 16);
      h_lds[ob][oj + 1] = (u16)(dv >> 48);
    }
    __syncthreads();
  }
  // save state for next chunk
  {
    size_t si = (size_t)(B0 + wv) * 256;
    cstate[si + j0] = cst[0]; cstate[si + j0 + 64] = cst[1];
    hstate[si + j0] = hp[0];  hstate[si + j0 + 64] = hp[1];
  }
}

// ---------------- rotation prefix scan ----------------

__device__ inline void mat3mul(float* __restrict__ o, const float* a, const float* b) {
#pragma unroll
  for (int i = 0; i < 3; ++i)
#pragma unroll
    for (int j = 0; j < 3; ++j)
      o[i * 3 + j] = a[i * 3 + 0] * b[0 * 3 + j] + a[i * 3 + 1] * b[1 * 3 + j] + a[i * 3 + 2] * b[2 * 3 + j];
}

__device__ inline void rodrigues(float w1, float w2, float w3, float* R) {
  float t2 = w1 * w1 + w2 * w2 + w3 * w3;
  float A, Bc;
  if (t2 < 1e-8f) {
    A = 1.f - t2 * (1.f / 6.f);
    Bc = 0.5f - t2 * (1.f / 24.f);
  } else {
    float th = sqrtf(t2);
    A = __sinf(th) / th;
    Bc = (1.f - __cosf(th)) / t2;
  }
  float c_ = 1.f - Bc * t2;
  R[0] = c_ + Bc * w1 * w1; R[1] = Bc * w1 * w2 - A * w3; R[2] = Bc * w1 * w3 + A * w2;
  R[3] = Bc * w1 * w2 + A * w3; R[4] = c_ + Bc * w2 * w2; R[5] = Bc * w2 * w3 - A * w1;
  R[6] = Bc * w1 * w3 - A * w2; R[7] = Bc * w2 * w3 + A * w1; R[8] = c_ + Bc * w3 * w3;
}

__global__ __launch_bounds__(256) void rotscan_kernel(const float* __restrict__ wpart,
                                                      float* __restrict__ out) {
  __shared__ float buf[2][256][9];
  int b = blockIdx.x, tid = threadIdx.x;
  const float* w0 = wpart + (size_t)b * 2047 * 3;
  const float* w1 = wpart + (size_t)64 * 2047 * 3 + (size_t)b * 2047 * 3;
  float R[8][9];
  float C[9] = {1, 0, 0, 0, 1, 0, 0, 0, 1};
#pragma unroll
  for (int s = 0; s < 8; ++s) {
    int idx = tid * 8 + s;
    float wx = 0.f, wy = 0.f, wz = 0.f;
    if (idx < 2047) {
      wx = w0[idx * 3 + 0] + w1[idx * 3 + 0];
      wy = w0[idx * 3 + 1] + w1[idx * 3 + 1];
      wz = w0[idx * 3 + 2] + w1[idx * 3 + 2];
    }
    rodrigues(wx, wy, wz, R[s]);
    float T_[9];
    mat3mul(T_, C, R[s]);
#pragma unroll
    for (int e = 0; e < 9; ++e) C[e] = T_[e];
  }
#pragma unroll
  for (int e = 0; e < 9; ++e) buf[0][tid][e] = C[e];
  __syncthreads();
  int p = 0;
  for (int d = 1; d < 256; d <<= 1) {
    float L[9];
    if (tid >= d) {
      mat3mul(L, buf[p][tid - d], buf[p][tid]);
    } else {
#pragma unroll
      for (int e = 0; e < 9; ++e) L[e] = buf[p][tid][e];
    }
#pragma unroll
    for (int e = 0; e < 9; ++e) buf[p ^ 1][tid][e] = L[e];
    __syncthreads();
    p ^= 1;
  }
  float P[9];
  if (tid == 0) {
    P[0] = 1; P[1] = 0; P[2] = 0; P[3] = 0; P[4] = 1; P[5] = 0; P[6] = 0; P[7] = 0; P[8] = 1;
  } else {
#pragma unroll
    for (int e = 0; e < 9; ++e) P[e] = buf[p][tid - 1][e];
  }
#pragma unroll
  for (int s = 0; s < 8; ++s) {
    float Q[9];
    mat3mul(Q, P, R[s]);
#pragma unroll
    for (int e = 0; e < 9; ++e) P[e] = Q[e];
    int idx = tid * 8 + s;
    if (idx < 2047) {
      size_t o = ((size_t)b * 2047 + idx) * 3;
      out[o + 0] = P[2]; out[o + 1] = P[5]; out[o + 2] = P[8];
    }
  }
}

// ---------------- launch ----------------

extern "C" void kernel_launch(void* const* d_in, const int* in_sizes, int n_in,
                              void* d_out, int out_size, void* d_ws, size_t ws_size,
                              hipStream_t stream) {
  const float* X    = (const float*)d_in[0];
  const float* w1   = (const float*)d_in[1];
  const float* b1   = (const float*)d_in[2];
  const float* w2   = (const float*)d_in[3];
  const float* b2   = (const float*)d_in[4];
  const float* Wih  = (const float*)d_in[5];
  const float* Whh  = (const float*)d_in[6];
  const float* bih  = (const float*)d_in[7];
  const float* bhh  = (const float*)d_in[8];
  const float* fc2w = (const float*)d_in[9];
  const float* devw = (const float*)d_in[11];
  float* out = (float*)d_out;

  char* ws = (char*)d_ws;
  size_t off = 0;
  auto take = [&](size_t bytes) { size_t p = off; off = (off + bytes + 255) & ~255ULL; return p; };
  size_t oW2b   = take((size_t)256 * 256 * 2);
  size_t oWIHb  = take((size_t)1024 * 256 * 2);
  size_t oG     = take((size_t)256 * 3 * 4);
  size_t oWPART = take((size_t)2 * 64 * 2047 * 3 * 4);
  size_t oHX    = take((size_t)8 * 2 * 8 * 256 * 4);
  size_t oCST   = take((size_t)64 * 256 * 4);
  size_t oHST   = take((size_t)64 * 256 * 4);
  size_t fixed = off;

  int Tc = 2048, tcl2 = 11;
  while (Tc > 2 && fixed + (size_t)Tc * 196608 + 1024 > ws_size) { Tc >>= 1; --tcl2; }
  if (fixed + (size_t)Tc * 196608 + 1024 > ws_size) return;  // ws < ~4.5 MB: impossible

  size_t oH1 = take((size_t)64 * Tc * 256 * 2);
  size_t oY2 = take((size_t)64 * Tc * 256 * 2);
  size_t oXG = take((size_t)64 * Tc * 1024 * 2);

  u16* W2b     = (u16*)(ws + oW2b);
  u16* WIHb    = (u16*)(ws + oWIHb);
  float* G     = (float*)(ws + oG);
  float* WPART = (float*)(ws + oWPART);
  u32* HX      = (u32*)(ws + oHX);
  float* CST   = (float*)(ws + oCST);
  float* HST   = (float*)(ws + oHST);
  u16* H1      = (u16*)(ws + oH1);
  u16* Y2      = (u16*)(ws + oY2);
  u16* XG      = (u16*)(ws + oXG);

  cvt_bf16<<<dim3(64), dim3(256), 0, stream>>>(w2, W2b, 256 * 256);
  cvt_bf16<<<dim3(256), dim3(256), 0, stream>>>(Wih, WIHb, 1024 * 256);
  gmat_kernel<<<dim3(1), dim3(256), 0, stream>>>(fc2w, devw, G);

  int NC = 2048 / Tc;
  int mb = (64 * Tc) / 128;
  for (int c = 0; c < NC; ++c) {
    int t0 = c * Tc;
    fc1_kernel<<<dim3(Tc), dim3(256), 0, stream>>>(X, w1, b1, H1, t0, tcl2);
    gemm_k256<<<dim3(mb * 4), dim3(256), 0, stream>>>(H1, W2b, b2, (const float*)nullptr, Y2, 256, 1);
    gemm_k256<<<dim3(mb * 16), dim3(256), 0, stream>>>(Y2, WIHb, bih, bhh, XG, 1024, 0);
    lstm_kernel<<<dim3(16), dim3(512), 0, stream>>>(XG, Whh, G, WPART, HX, CST, HST, t0, Tc);
  }
  rotscan_kernel<<<dim3(64), dim3(256), 0, stream>>>(WPART, out);
}